// Round 1
// baseline (68.341 us; speedup 1.0000x reference)
//
#include <hip/hip_runtime.h>

// BitLayer: y[n,b] = OR_i ( x[i,b] & (u[i,n,b] < kernel[i,n]) )
// u = jax.random.uniform(jax.random.key(42), (1024,1024,256), f32), threefry2x32.
//
// Strategy (v2): a wave (64 lanes = 64 consecutive n, same b) statistically
// always satisfies all lanes within the first ~20 rows of i (per active row,
// lane success prob ~U(0,1); P(wave needs >32 rows) ~ 64*2^-16). So:
//   - hoist rows 0..31 entirely into registers up front: 32 coalesced kern
//     loads per lane + 32 block-uniform x loads (compiler -> s_load). ONE
//     latency wait, then pure VALU.
//   - exit check __all(done) every 2 rows (was every 8) to cut threefry
//     overshoot; all array indices are literal constants (registers, not
//     scratch).
//   - rare fallback loop (batch 8) for waves not done after 32 rows; keeps
//     the general i>=512 counter-lane select for full correctness.
// RNG formula identical to the absmax=0-verified version.

#define INPUT_DIM 1024
#define NUM_OUTPUTS 1024
#define BIT_SIZE 256
#define CHUNK 32

__device__ __forceinline__ uint32_t rotl32(uint32_t v, int r) {
    return (v << r) | (v >> (32 - r));
}

// JAX threefry2x32: key (k0,k1), counter (x0,x1) -> 2 output words in-place.
__device__ __forceinline__ void threefry2x32(uint32_t k0, uint32_t k1,
                                             uint32_t& x0, uint32_t& x1) {
    const uint32_t ks0 = k0;
    const uint32_t ks1 = k1;
    const uint32_t ks2 = k0 ^ k1 ^ 0x1BD11BDAu;
    x0 += ks0;
    x1 += ks1;
#define TF_ROUND(r) { x0 += x1; x1 = rotl32(x1, (r)); x1 ^= x0; }
    TF_ROUND(13) TF_ROUND(15) TF_ROUND(26) TF_ROUND(6)
    x0 += ks1; x1 += ks2 + 1u;
    TF_ROUND(17) TF_ROUND(29) TF_ROUND(16) TF_ROUND(24)
    x0 += ks2; x1 += ks0 + 2u;
    TF_ROUND(13) TF_ROUND(15) TF_ROUND(26) TF_ROUND(6)
    x0 += ks0; x1 += ks1 + 3u;
    TF_ROUND(17) TF_ROUND(29) TF_ROUND(16) TF_ROUND(24)
    x0 += ks1; x1 += ks2 + 4u;
    TF_ROUND(13) TF_ROUND(15) TF_ROUND(26) TF_ROUND(6)
    x0 += ks2; x1 += ks0 + 5u;
#undef TF_ROUND
}

// Grid: 1024 blocks = 256 b x 4 n-chunks; 256 threads (consecutive n).
__global__ __launch_bounds__(256) void BitLayer_25391846654323_kernel(
        const int* __restrict__ x,         // (1024, 256) int32 0/1
        const float* __restrict__ kern,    // (1024, 1024) f32 probs
        float* __restrict__ out) {         // (1024, 256) f32 0/1
    const int tid = threadIdx.x;
    const int b = blockIdx.x >> 2;                         // 0..255
    const int n = ((blockIdx.x & 3) << 8) + tid;           // 0..1023
    const uint32_t nb = ((uint32_t)n << 8) | (uint32_t)b;

    // Hoist rows 0..CHUNK-1 into registers. x loads are block-uniform
    // (b uniform) -> scalar loads; kern loads are coalesced across lanes.
    // Static trip count + full unroll -> all indices literal -> registers.
    int   xs[CHUNK];
    float pr[CHUNK];
#pragma unroll
    for (int k = 0; k < CHUNK; ++k) {
        xs[k] = x[(k << 8) + b];           // wave-uniform broadcast / s_load
        pr[k] = kern[(k << 10) + n];       // coalesced
    }

    uint32_t done = 0;

    // One trial, i = k (k < 512 always here, so counter lane0 word is used).
#define TRIAL(k)                                                            \
    if (xs[k] != 0) {                                                       \
        uint32_t c0 = (((uint32_t)(k)) << 18) | nb;                         \
        uint32_t c1 = c0 + (1u << 27);                                      \
        threefry2x32(0u, 42u, c0, c1);                                      \
        const float u = (float)(c0 >> 9) * 0x1p-23f;                        \
        if (u < pr[k]) done = 1u;                                           \
    }
#define PAIR(a, c)  TRIAL(a) TRIAL(c) if (__all(done != 0)) goto finish;

    PAIR(0, 1)   PAIR(2, 3)   PAIR(4, 5)   PAIR(6, 7)
    PAIR(8, 9)   PAIR(10, 11) PAIR(12, 13) PAIR(14, 15)
    PAIR(16, 17) PAIR(18, 19) PAIR(20, 21) PAIR(22, 23)
    PAIR(24, 25) PAIR(26, 27) PAIR(28, 29) PAIR(30, 31)
#undef PAIR
#undef TRIAL

    // Rare fallback: some lane in this wave is still unsatisfied after
    // CHUNK rows (P ~ 2^-16 per lane). Simple batch-8 scan of the rest;
    // keeps the general counter-lane select for i >= 512.
    for (int i0 = CHUNK; i0 < INPUT_DIM; i0 += 8) {
        int   xb2[8];
        float p2[8];
#pragma unroll
        for (int k = 0; k < 8; ++k) {
            xb2[k] = x[((i0 + k) << 8) + b];
            p2[k]  = kern[((i0 + k) << 10) + n];
        }
#pragma unroll
        for (int k = 0; k < 8; ++k) {
            if (xb2[k] != 0) {             // wave-uniform branch (b uniform)
                const int i = i0 + k;
                // linear index into u: jdx = i*2^18 + n*2^8 + b.  H = 2^27.
                // jdx <  H (i<512): bits = lane0 of threefry((jdx, jdx+H))
                // jdx >= H        : bits = lane1 of threefry((jdx-H, jdx))
                uint32_t c0 = (((uint32_t)(i & 511)) << 18) | nb;
                uint32_t c1 = c0 + (1u << 27);
                threefry2x32(0u, 42u, c0, c1);
                const uint32_t bits = (i < 512) ? c0 : c1;
                const float u = (float)(bits >> 9) * 0x1p-23f;
                if (u < p2[k]) done = 1u;
            }
        }
        if (__all(done != 0)) break;       // whole wave satisfied
    }

finish:
    out[((uint32_t)n << 8) + (uint32_t)b] = done ? 1.0f : 0.0f;
}

extern "C" void kernel_launch(void* const* d_in, const int* in_sizes, int n_in,
                              void* d_out, int out_size, void* d_ws, size_t ws_size,
                              hipStream_t stream) {
    const int* x = (const int*)d_in[0];          // (1024, 256) int32
    const float* kern = (const float*)d_in[1];   // (1024, 1024) f32
    float* out = (float*)d_out;                  // (1024, 256) f32

    BitLayer_25391846654323_kernel<<<NUM_OUTPUTS, 256, 0, stream>>>(x, kern, out);
}

// Round 2
// 64.261 us; speedup vs baseline: 1.0635x; 1.0635x over previous
//
#include <hip/hip_runtime.h>

// BitLayer: y[n,b] = OR_i ( x[i,b] & (u[i,n,b] < kernel[i,n]) )
// u = jax.random.uniform(jax.random.key(42), (1024,1024,256), f32), threefry2x32.
//
// v3: PAIR TRICK. JAX draws u for linear index jdx = i*2^18 + n*2^8 + b via
// threefry counter pair (jdx, jdx + 2^27) for jdx < 2^27: output word0 is
// u[jdx], word1 is u[jdx + 2^27] = u for row i+512 (same n,b). One threefry
// therefore serves rows i AND i+512 -> half the threefry calls for the same
// trial count. Additionally skip the call when neither row's x-bit is set
// (1/4 of pairs; wave-uniform branch since b is block-uniform).
//
//   - hoist pairs k=0..15 (rows 0..15 and 512..527) into registers up front:
//     32 coalesced kern loads + 32 block-uniform x loads (-> s_load).
//   - exit check __all(done) every 2 pairs; indices all literal -> registers.
//   - rare fallback loop (8 pairs/iter) for waves not satisfied after 16
//     pairs (~32 potential / ~16 active trials; P ~ 64*2^-16 per wave).
// RNG formulas byte-identical to the absmax=0-verified versions.

#define INPUT_DIM 1024
#define NUM_OUTPUTS 1024
#define BIT_SIZE 256
#define NPAIR 16

__device__ __forceinline__ uint32_t rotl32(uint32_t v, int r) {
    return (v << r) | (v >> (32 - r));
}

// JAX threefry2x32: key (k0,k1), counter (x0,x1) -> 2 output words in-place.
__device__ __forceinline__ void threefry2x32(uint32_t k0, uint32_t k1,
                                             uint32_t& x0, uint32_t& x1) {
    const uint32_t ks0 = k0;
    const uint32_t ks1 = k1;
    const uint32_t ks2 = k0 ^ k1 ^ 0x1BD11BDAu;
    x0 += ks0;
    x1 += ks1;
#define TF_ROUND(r) { x0 += x1; x1 = rotl32(x1, (r)); x1 ^= x0; }
    TF_ROUND(13) TF_ROUND(15) TF_ROUND(26) TF_ROUND(6)
    x0 += ks1; x1 += ks2 + 1u;
    TF_ROUND(17) TF_ROUND(29) TF_ROUND(16) TF_ROUND(24)
    x0 += ks2; x1 += ks0 + 2u;
    TF_ROUND(13) TF_ROUND(15) TF_ROUND(26) TF_ROUND(6)
    x0 += ks0; x1 += ks1 + 3u;
    TF_ROUND(17) TF_ROUND(29) TF_ROUND(16) TF_ROUND(24)
    x0 += ks1; x1 += ks2 + 4u;
    TF_ROUND(13) TF_ROUND(15) TF_ROUND(26) TF_ROUND(6)
    x0 += ks2; x1 += ks0 + 5u;
#undef TF_ROUND
}

// Grid: 1024 blocks = 256 b x 4 n-chunks; 256 threads (consecutive n).
__global__ __launch_bounds__(256) void BitLayer_25391846654323_kernel(
        const int* __restrict__ x,         // (1024, 256) int32 0/1
        const float* __restrict__ kern,    // (1024, 1024) f32 probs
        float* __restrict__ out) {         // (1024, 256) f32 0/1
    const int tid = threadIdx.x;
    const int b = blockIdx.x >> 2;                         // 0..255
    const int n = ((blockIdx.x & 3) << 8) + tid;           // 0..1023
    const uint32_t nb = ((uint32_t)n << 8) | (uint32_t)b;

    // Hoist pairs 0..NPAIR-1 (rows k and k+512). x loads block-uniform
    // (-> scalar); kern loads coalesced. Full unroll -> literal indices.
    int   xl[NPAIR], xh[NPAIR];
    float pl[NPAIR], ph[NPAIR];
#pragma unroll
    for (int k = 0; k < NPAIR; ++k) {
        xl[k] = x[(k << 8) + b];
        xh[k] = x[((k + 512) << 8) + b];
        pl[k] = kern[(k << 10) + n];
        ph[k] = kern[((k + 512) << 10) + n];
    }

    uint32_t done = 0;

    // One threefry serves rows k (word0) and k+512 (word1).
#define PAIRTRIAL(k)                                                        \
    if ((xl[k] | xh[k]) != 0) {                                             \
        uint32_t c0 = (((uint32_t)(k)) << 18) | nb;                         \
        uint32_t c1 = c0 + (1u << 27);                                      \
        threefry2x32(0u, 42u, c0, c1);                                      \
        if (xl[k] && ((float)(c0 >> 9) * 0x1p-23f < pl[k])) done = 1u;      \
        if (xh[k] && ((float)(c1 >> 9) * 0x1p-23f < ph[k])) done = 1u;      \
    }
#define STEP(a, c)  PAIRTRIAL(a) PAIRTRIAL(c) if (__all(done != 0)) goto finish;

    STEP(0, 1)   STEP(2, 3)   STEP(4, 5)   STEP(6, 7)
    STEP(8, 9)   STEP(10, 11) STEP(12, 13) STEP(14, 15)
#undef STEP
#undef PAIRTRIAL

    // Rare fallback: scan remaining pairs (rows i & i+512 for i=16..511).
    for (int i0 = NPAIR; i0 < 512; i0 += 8) {
        int   xl2[8], xh2[8];
        float pl2[8], ph2[8];
#pragma unroll
        for (int k = 0; k < 8; ++k) {
            xl2[k] = x[((i0 + k) << 8) + b];
            xh2[k] = x[((i0 + k + 512) << 8) + b];
            pl2[k] = kern[((i0 + k) << 10) + n];
            ph2[k] = kern[((i0 + k + 512) << 10) + n];
        }
#pragma unroll
        for (int k = 0; k < 8; ++k) {
            if ((xl2[k] | xh2[k]) != 0) {      // wave-uniform branch
                uint32_t c0 = (((uint32_t)(i0 + k)) << 18) | nb;
                uint32_t c1 = c0 + (1u << 27);
                threefry2x32(0u, 42u, c0, c1);
                if (xl2[k] && ((float)(c0 >> 9) * 0x1p-23f < pl2[k])) done = 1u;
                if (xh2[k] && ((float)(c1 >> 9) * 0x1p-23f < ph2[k])) done = 1u;
            }
        }
        if (__all(done != 0)) break;           // whole wave satisfied
    }

finish:
    out[((uint32_t)n << 8) + (uint32_t)b] = done ? 1.0f : 0.0f;
}

extern "C" void kernel_launch(void* const* d_in, const int* in_sizes, int n_in,
                              void* d_out, int out_size, void* d_ws, size_t ws_size,
                              hipStream_t stream) {
    const int* x = (const int*)d_in[0];          // (1024, 256) int32
    const float* kern = (const float*)d_in[1];   // (1024, 1024) f32
    float* out = (float*)d_out;                  // (1024, 256) f32

    BitLayer_25391846654323_kernel<<<NUM_OUTPUTS, 256, 0, stream>>>(x, kern, out);
}